// Round 1
// baseline (396.732 us; speedup 1.0000x reference)
//
#include <hip/hip_runtime.h>
#include <hip/hip_bf16.h>

#define DM 1024
#define NH 16
#define HD 64
#define BATCH 2
#define SEQ 2048
#define MROWS (BATCH*SEQ)   // 4096

typedef __attribute__((ext_vector_type(8))) short bf16x8;
typedef __attribute__((ext_vector_type(4))) float f32x4;

__device__ __forceinline__ short f2b(float f) {
  union { float f; unsigned u; } x; x.f = f;
  unsigned r = x.u + 0x7fffu + ((x.u >> 16) & 1u);
  return (short)(r >> 16);
}

__device__ __forceinline__ void gload16(const void* g, void* l) {
  __builtin_amdgcn_global_load_lds((const __attribute__((address_space(1))) unsigned int*)g,
                                   (__attribute__((address_space(3))) unsigned int*)l, 16, 0, 0);
}

// ---------------- prep kernels ----------------

__global__ void k_conv(const float* __restrict__ src, short* __restrict__ dst, int n) {
  int i = (blockIdx.x * 256 + threadIdx.x) * 8;
  if (i >= n) return;
  const float4* s4 = (const float4*)(src + i);
  float4 a = s4[0], b = s4[1];
  bf16x8 o;
  o[0]=f2b(a.x); o[1]=f2b(a.y); o[2]=f2b(a.z); o[3]=f2b(a.w);
  o[4]=f2b(b.x); o[5]=f2b(b.y); o[6]=f2b(b.z); o[7]=f2b(b.w);
  *(bf16x8*)(dst + i) = o;
}

// Wq rows scaled by sigmoid(gate[row]) (gate is (16,64) flat = 1024 = row index)
__global__ void k_conv_gate(const float* __restrict__ Wq, const float* __restrict__ gate,
                            short* __restrict__ dst) {
  int i = (blockIdx.x * 256 + threadIdx.x) * 8;
  int row = i >> 10;
  float sg = 1.f / (1.f + __expf(-gate[row]));
  const float4* s4 = (const float4*)(Wq + i);
  float4 a = s4[0], b = s4[1];
  bf16x8 o;
  o[0]=f2b(a.x*sg); o[1]=f2b(a.y*sg); o[2]=f2b(a.z*sg); o[3]=f2b(a.w*sg);
  o[4]=f2b(b.x*sg); o[5]=f2b(b.y*sg); o[6]=f2b(b.z*sg); o[7]=f2b(b.w*sg);
  *(bf16x8*)(dst + i) = o;
}

// Wk_ent[h*64+e][c] = sum_d ent[h][d][e] * Wk[h*64+d][c]
__global__ void k_went(const float* __restrict__ Wk, const float* __restrict__ ent,
                       short* __restrict__ dst) {
  int r = blockIdx.x;            // 0..1023
  int h = r >> 6, e = r & 63;
  int c = blockIdx.y * 256 + threadIdx.x;
  float acc = 0.f;
#pragma unroll 8
  for (int d = 0; d < 64; ++d)
    acc += ent[h*4096 + d*64 + e] * Wk[(size_t)(h*64 + d)*DM + c];
  dst[(size_t)r*DM + c] = f2b(acc);
}

__global__ void k_bias(const float* __restrict__ bq, const float* __restrict__ bk,
                       const float* __restrict__ bv, const float* __restrict__ gate,
                       const float* __restrict__ ent, float* __restrict__ bcat) {
  int i = blockIdx.x * 256 + threadIdx.x;  // < 3072
  float v;
  if (i < 1024) {
    v = bq[i] * (1.f / (1.f + __expf(-gate[i])));
  } else if (i < 2048) {
    int rr = i - 1024, h = rr >> 6, e = rr & 63;
    float a = 0.f;
    for (int d = 0; d < 64; ++d) a += bk[h*64 + d] * ent[h*4096 + d*64 + e];
    v = a;
  } else {
    v = bv[i - 2048];
  }
  bcat[i] = v;
}

// ---------------- GEMM: C[m,n] = sum_k A[m,k]*B[n,k] + bias[n] ----------------
// A: MxK bf16 row-major, B: NxK bf16 row-major. 128x128 tile, BK=64, 4 waves.

template<int OUT_BF16>
__global__ __launch_bounds__(256) void gemm_bt(const short* __restrict__ A,
                                               const short* __restrict__ B,
                                               const float* __restrict__ bias,
                                               void* __restrict__ C,
                                               int M, int N, int K) {
  __shared__ __align__(16) short As[128*64];
  __shared__ __align__(16) short Bs[128*64];
  const int t = threadIdx.x, l = t & 63, w = t >> 6;
  const int wr = w >> 1, wc = w & 1;
  const int bm = blockIdx.x, bn = blockIdx.y;
  const int row_l = l & 15, kg = l >> 4;
  f32x4 acc[4][4];
  {
    f32x4 z = {0.f, 0.f, 0.f, 0.f};
#pragma unroll
    for (int m = 0; m < 4; ++m)
#pragma unroll
      for (int n = 0; n < 4; ++n) acc[m][n] = z;
  }
  for (int k0 = 0; k0 < K; k0 += 64) {
#pragma unroll
    for (int i = 0; i < 4; ++i) {
      int idx = i * 256 + t;
      int row = idx >> 3, cb = (idx & 7) * 8;
      gload16(A + (size_t)(bm*128 + row)*K + k0 + cb, &As[idx*8]);
      gload16(B + (size_t)(bn*128 + row)*K + k0 + cb, &Bs[idx*8]);
    }
    __syncthreads();
#pragma unroll
    for (int ks = 0; ks < 2; ++ks) {
      bf16x8 af[4], bfv[4];
#pragma unroll
      for (int m = 0; m < 4; ++m)
        af[m] = *(const bf16x8*)&As[(wr*64 + m*16 + row_l)*64 + ks*32 + kg*8];
#pragma unroll
      for (int n = 0; n < 4; ++n)
        bfv[n] = *(const bf16x8*)&Bs[(wc*64 + n*16 + row_l)*64 + ks*32 + kg*8];
#pragma unroll
      for (int m = 0; m < 4; ++m)
#pragma unroll
        for (int n = 0; n < 4; ++n)
          acc[m][n] = __builtin_amdgcn_mfma_f32_16x16x32_bf16(af[m], bfv[n], acc[m][n], 0, 0, 0);
    }
    __syncthreads();
  }
  const int r0 = bm*128 + wr*64, c0 = bn*128 + wc*64;
#pragma unroll
  for (int n = 0; n < 4; ++n) {
    int col = c0 + n*16 + row_l;
    float bvs = bias[col];
#pragma unroll
    for (int m = 0; m < 4; ++m) {
#pragma unroll
      for (int r = 0; r < 4; ++r) {
        int row = r0 + m*16 + kg*4 + r;
        float v = acc[m][n][r] + bvs;
        if (OUT_BF16) ((short*)C)[(size_t)row*N + col] = f2b(v);
        else          ((float*)C)[(size_t)row*N + col] = v;
      }
    }
  }
}

// ---------------- fused attention ----------------
// QKV: (4096 x 3072) bf16; per (b,h): Q at col h*64, K' at 1024+h*64, V at 2048+h*64.
// Block: 4 waves, 64 q-rows of one (b,h). Writes normalized attn (fp32) + ctx (bf16).

__global__ __launch_bounds__(256) void attn_fused(const short* __restrict__ QKV,
                                                  float* __restrict__ attn_out,
                                                  short* __restrict__ ctx) {
  __shared__ __align__(16) short Ks[64*72];
  __shared__ __align__(16) short Vt[64*72];
  __shared__ __align__(16) float Ps[4][16][36];
  const int t = threadIdx.x, l = t & 63, w = t >> 6;
  const int row_l = l & 15, kg = l >> 4;
  const int blk = blockIdx.x;
  const int bh = blk >> 5, q0 = (blk & 31) * 64;
  const int b = bh >> 4, h = bh & 15;
  const short* Qp = QKV + (size_t)b*SEQ*3072 + h*64;
  const short* Kp = Qp + DM;
  const short* Vp = Qp + 2*DM;
  float* attn_bh = attn_out + (size_t)bh * SEQ * SEQ;
  const int qw = q0 + w*16;

  bf16x8 aq0 = *(const bf16x8*)(Qp + (size_t)(qw + row_l)*3072 + kg*8);
  bf16x8 aq1 = *(const bf16x8*)(Qp + (size_t)(qw + row_l)*3072 + 32 + kg*8);

  float rsum[4] = {0.f, 0.f, 0.f, 0.f};
  // ---- pass 1: row sums of exp(s) (no max subtraction: |s| <= ~8, fp32-safe) ----
  for (int kt = 0; kt < 32; ++kt) {
#pragma unroll
    for (int i = 0; i < 2; ++i) {
      int idx = i*256 + t;
      int kr = idx >> 3, cb = (idx & 7) * 8;
      *(bf16x8*)&Ks[kr*72 + cb] = *(const bf16x8*)(Kp + (size_t)(kt*64 + kr)*3072 + cb);
    }
    __syncthreads();
#pragma unroll
    for (int nt = 0; nt < 4; ++nt) {
      bf16x8 bk0 = *(const bf16x8*)&Ks[(nt*16 + row_l)*72 + kg*8];
      bf16x8 bk1 = *(const bf16x8*)&Ks[(nt*16 + row_l)*72 + 32 + kg*8];
      f32x4 s = {0.f, 0.f, 0.f, 0.f};
      s = __builtin_amdgcn_mfma_f32_16x16x32_bf16(aq0, bk0, s, 0, 0, 0);
      s = __builtin_amdgcn_mfma_f32_16x16x32_bf16(aq1, bk1, s, 0, 0, 0);
#pragma unroll
      for (int r = 0; r < 4; ++r) rsum[r] += __expf(s[r] * 0.125f);
    }
    __syncthreads();
  }
#pragma unroll
  for (int m = 1; m < 16; m <<= 1)
#pragma unroll
    for (int r = 0; r < 4; ++r) rsum[r] += __shfl_xor(rsum[r], m);
  float inv[4];
#pragma unroll
  for (int r = 0; r < 4; ++r) inv[r] = 1.f / rsum[r];

  f32x4 actx[4];
  {
    f32x4 z = {0.f, 0.f, 0.f, 0.f};
#pragma unroll
    for (int e = 0; e < 4; ++e) actx[e] = z;
  }
  // ---- pass 2: recompute scores, write normalized attn, accumulate P@V ----
  for (int kt = 0; kt < 32; ++kt) {
#pragma unroll
    for (int i = 0; i < 2; ++i) {
      int idx = i*256 + t;
      int kr = idx >> 3, cb = (idx & 7) * 8;
      *(bf16x8*)&Ks[kr*72 + cb] = *(const bf16x8*)(Kp + (size_t)(kt*64 + kr)*3072 + cb);
      bf16x8 vv = *(const bf16x8*)(Vp + (size_t)(kt*64 + kr)*3072 + cb);
#pragma unroll
      for (int j = 0; j < 8; ++j) Vt[(cb + j)*72 + kr] = vv[j];
    }
    __syncthreads();
#pragma unroll
    for (int half = 0; half < 2; ++half) {
#pragma unroll
      for (int nt2 = 0; nt2 < 2; ++nt2) {
        int nt = half*2 + nt2;
        bf16x8 bk0 = *(const bf16x8*)&Ks[(nt*16 + row_l)*72 + kg*8];
        bf16x8 bk1 = *(const bf16x8*)&Ks[(nt*16 + row_l)*72 + 32 + kg*8];
        f32x4 s = {0.f, 0.f, 0.f, 0.f};
        s = __builtin_amdgcn_mfma_f32_16x16x32_bf16(aq0, bk0, s, 0, 0, 0);
        s = __builtin_amdgcn_mfma_f32_16x16x32_bf16(aq1, bk1, s, 0, 0, 0);
        int key = kt*64 + nt*16 + row_l;
#pragma unroll
        for (int r = 0; r < 4; ++r) {
          float p = __expf(s[r] * 0.125f) * inv[r];
          attn_bh[(size_t)(qw + kg*4 + r)*SEQ + key] = p;
          Ps[w][kg*4 + r][nt2*16 + row_l] = p;
        }
      }
      __syncthreads();
      bf16x8 pa;
      {
        const float* prow = &Ps[w][row_l][kg*8];
#pragma unroll
        for (int j = 0; j < 8; ++j) pa[j] = f2b(prow[j]);
      }
#pragma unroll
      for (int e = 0; e < 4; ++e) {
        bf16x8 bv = *(const bf16x8*)&Vt[(e*16 + row_l)*72 + half*32 + kg*8];
        actx[e] = __builtin_amdgcn_mfma_f32_16x16x32_bf16(pa, bv, actx[e], 0, 0, 0);
      }
      __syncthreads();
    }
  }
  // ctx epilogue: (b*2048+q, h*64+e) bf16
#pragma unroll
  for (int e = 0; e < 4; ++e)
#pragma unroll
    for (int r = 0; r < 4; ++r)
      ctx[(size_t)(b*SEQ + qw + kg*4 + r)*DM + h*64 + e*16 + row_l] = f2b(actx[e][r]);
}

// ---------------- launch ----------------

extern "C" void kernel_launch(void* const* d_in, const int* in_sizes, int n_in,
                              void* d_out, int out_size, void* d_ws, size_t ws_size,
                              hipStream_t stream) {
  const float* x    = (const float*)d_in[0];
  const float* Wq   = (const float*)d_in[1];
  const float* bq   = (const float*)d_in[2];
  const float* Wk   = (const float*)d_in[3];
  const float* bk   = (const float*)d_in[4];
  const float* Wv   = (const float*)d_in[5];
  const float* bv   = (const float*)d_in[6];
  const float* Wo   = (const float*)d_in[7];
  const float* bo   = (const float*)d_in[8];
  const float* gate = (const float*)d_in[9];
  const float* ent  = (const float*)d_in[10];

  char* ws = (char*)d_ws;
  short* xb   = (short*)(ws);                          // 4096x1024 bf16 (8 MB)
  short* Wcat = (short*)(ws + ((size_t)8  << 20));     // 3072x1024 bf16 (6 MB)
  short* Wob  = (short*)(ws + ((size_t)14 << 20));     // 1024x1024 bf16 (2 MB)
  float* bcat = (float*)(ws + ((size_t)16 << 20));     // 3072 f32
  short* QKV  = (short*)(ws + ((size_t)17 << 20));     // 4096x3072 bf16 (24 MB)
  short* ctxb = (short*)(ws + ((size_t)41 << 20));     // 4096x1024 bf16 (8 MB)

  float* outp  = (float*)d_out;
  float* attnp = outp + (size_t)MROWS * DM;

  k_conv<<<2048, 256, 0, stream>>>(x, xb, MROWS*DM);
  k_conv_gate<<<512, 256, 0, stream>>>(Wq, gate, Wcat);
  k_went<<<dim3(1024, 4), 256, 0, stream>>>(Wk, ent, Wcat + (size_t)1024*DM);
  k_conv<<<512, 256, 0, stream>>>(Wv, Wcat + (size_t)2048*DM, 1024*1024);
  k_conv<<<512, 256, 0, stream>>>(Wo, Wob, 1024*1024);
  k_bias<<<12, 256, 0, stream>>>(bq, bk, bv, gate, ent, bcat);

  gemm_bt<1><<<dim3(32, 24), 256, 0, stream>>>(xb, Wcat, bcat, QKV, MROWS, 3072, DM);
  attn_fused<<<1024, 256, 0, stream>>>(QKV, attnp, ctxb);
  gemm_bt<0><<<dim3(32, 8), 256, 0, stream>>>(ctxb, Wob, bo, outp, MROWS, DM, DM);
}

// Round 2
// 340.822 us; speedup vs baseline: 1.1640x; 1.1640x over previous
//
#include <hip/hip_runtime.h>
#include <hip/hip_bf16.h>

#define DM 1024
#define NH 16
#define HD 64
#define BATCH 2
#define SEQ 2048
#define MROWS (BATCH*SEQ)   // 4096

typedef __attribute__((ext_vector_type(8))) short bf16x8;
typedef __attribute__((ext_vector_type(4))) short bf16x4;
typedef __attribute__((ext_vector_type(4))) float f32x4;

__device__ __forceinline__ short f2b(float f) {
  union { float f; unsigned u; } x; x.f = f;
  unsigned r = x.u + 0x7fffu + ((x.u >> 16) & 1u);
  return (short)(r >> 16);
}

__device__ __forceinline__ void gload16(const void* g, void* l) {
  __builtin_amdgcn_global_load_lds((const __attribute__((address_space(1))) unsigned int*)g,
                                   (__attribute__((address_space(3))) unsigned int*)l, 16, 0, 0);
}

// ---------------- prep kernels ----------------

__global__ void k_conv(const float* __restrict__ src, short* __restrict__ dst, int n) {
  int i = (blockIdx.x * 256 + threadIdx.x) * 8;
  if (i >= n) return;
  const float4* s4 = (const float4*)(src + i);
  float4 a = s4[0], b = s4[1];
  bf16x8 o;
  o[0]=f2b(a.x); o[1]=f2b(a.y); o[2]=f2b(a.z); o[3]=f2b(a.w);
  o[4]=f2b(b.x); o[5]=f2b(b.y); o[6]=f2b(b.z); o[7]=f2b(b.w);
  *(bf16x8*)(dst + i) = o;
}

__global__ void k_conv_gate(const float* __restrict__ Wq, const float* __restrict__ gate,
                            short* __restrict__ dst) {
  int i = (blockIdx.x * 256 + threadIdx.x) * 8;
  int row = i >> 10;
  float sg = 1.f / (1.f + __expf(-gate[row]));
  const float4* s4 = (const float4*)(Wq + i);
  float4 a = s4[0], b = s4[1];
  bf16x8 o;
  o[0]=f2b(a.x*sg); o[1]=f2b(a.y*sg); o[2]=f2b(a.z*sg); o[3]=f2b(a.w*sg);
  o[4]=f2b(b.x*sg); o[5]=f2b(b.y*sg); o[6]=f2b(b.z*sg); o[7]=f2b(b.w*sg);
  *(bf16x8*)(dst + i) = o;
}

// Wk_ent[h*64+e][c] = sum_d ent[h][d][e] * Wk[h*64+d][c]
__global__ void k_went(const float* __restrict__ Wk, const float* __restrict__ ent,
                       short* __restrict__ dst) {
  int r = blockIdx.x;            // 0..1023
  int h = r >> 6, e = r & 63;
  int c = blockIdx.y * 256 + threadIdx.x;
  float acc = 0.f;
#pragma unroll 8
  for (int d = 0; d < 64; ++d)
    acc += ent[h*4096 + d*64 + e] * Wk[(size_t)(h*64 + d)*DM + c];
  dst[(size_t)r*DM + c] = f2b(acc);
}

__global__ void k_bias(const float* __restrict__ bq, const float* __restrict__ bk,
                       const float* __restrict__ bv, const float* __restrict__ gate,
                       const float* __restrict__ ent, float* __restrict__ bcat) {
  int i = blockIdx.x * 256 + threadIdx.x;  // < 3072
  float v;
  if (i < 1024) {
    v = bq[i] * (1.f / (1.f + __expf(-gate[i])));
  } else if (i < 2048) {
    int rr = i - 1024, h = rr >> 6, e = rr & 63;
    float a = 0.f;
    for (int d = 0; d < 64; ++d) a += bk[h*64 + d] * ent[h*4096 + d*64 + e];
    v = a;
  } else {
    v = bv[i - 2048];
  }
  bcat[i] = v;
}

// ---------------- GEMM: C[m,n] = sum_k A[m,k]*B[n,k] + bias[n] ----------------

template<int OUT_BF16>
__global__ __launch_bounds__(256) void gemm_bt(const short* __restrict__ A,
                                               const short* __restrict__ B,
                                               const float* __restrict__ bias,
                                               void* __restrict__ C,
                                               int M, int N, int K) {
  __shared__ __align__(16) short As[128*64];
  __shared__ __align__(16) short Bs[128*64];
  const int t = threadIdx.x, l = t & 63, w = t >> 6;
  const int wr = w >> 1, wc = w & 1;
  const int bm = blockIdx.x, bn = blockIdx.y;
  const int row_l = l & 15, kg = l >> 4;
  f32x4 acc[4][4];
  {
    f32x4 z = {0.f, 0.f, 0.f, 0.f};
#pragma unroll
    for (int m = 0; m < 4; ++m)
#pragma unroll
      for (int n = 0; n < 4; ++n) acc[m][n] = z;
  }
  for (int k0 = 0; k0 < K; k0 += 64) {
#pragma unroll
    for (int i = 0; i < 4; ++i) {
      int idx = i * 256 + t;
      int row = idx >> 3, cb = (idx & 7) * 8;
      gload16(A + (size_t)(bm*128 + row)*K + k0 + cb, &As[idx*8]);
      gload16(B + (size_t)(bn*128 + row)*K + k0 + cb, &Bs[idx*8]);
    }
    __syncthreads();
#pragma unroll
    for (int ks = 0; ks < 2; ++ks) {
      bf16x8 af[4], bfv[4];
#pragma unroll
      for (int m = 0; m < 4; ++m)
        af[m] = *(const bf16x8*)&As[(wr*64 + m*16 + row_l)*64 + ks*32 + kg*8];
#pragma unroll
      for (int n = 0; n < 4; ++n)
        bfv[n] = *(const bf16x8*)&Bs[(wc*64 + n*16 + row_l)*64 + ks*32 + kg*8];
#pragma unroll
      for (int m = 0; m < 4; ++m)
#pragma unroll
        for (int n = 0; n < 4; ++n)
          acc[m][n] = __builtin_amdgcn_mfma_f32_16x16x32_bf16(af[m], bfv[n], acc[m][n], 0, 0, 0);
    }
    __syncthreads();
  }
  const int r0 = bm*128 + wr*64, c0 = bn*128 + wc*64;
#pragma unroll
  for (int n = 0; n < 4; ++n) {
    int col = c0 + n*16 + row_l;
    float bvs = bias[col];
#pragma unroll
    for (int m = 0; m < 4; ++m) {
#pragma unroll
      for (int r = 0; r < 4; ++r) {
        int row = r0 + m*16 + kg*4 + r;
        float v = acc[m][n][r] + bvs;
        if (OUT_BF16) ((short*)C)[(size_t)row*N + col] = f2b(v);
        else          ((float*)C)[(size_t)row*N + col] = v;
      }
    }
  }
}

// ---------------- fused attention (swapped-operand S^T form) ----------------
// QKV: (4096 x 3072) bf16; per (b,h): Q at col h*64, K' at 1024+h*64, V at 2048+h*64.
// Block: 4 waves, 64 q-rows of one (b,h). S^T = mfma(K,Q): lane holds
// q = lane&15, keys (lane>>4)*4+r. attn writes are float4; P relays through a
// per-wave LDS slab (no block barrier); PV computes ctx^T = V^T * P^T.

__global__ __launch_bounds__(256) void attn_fused(const short* __restrict__ QKV,
                                                  float* __restrict__ attn_out,
                                                  short* __restrict__ ctx) {
  __shared__ __align__(16) short Ks[64*72];
  __shared__ __align__(16) short Vt[64*72];
  __shared__ __align__(16) short Ps[4][16*72];   // per-wave P[q][key], stride 72
  const int t = threadIdx.x, l = t & 63, w = t >> 6;
  const int row_l = l & 15, kg = l >> 4;
  const int blk = blockIdx.x;
  const int bh = blk >> 5, q0 = (blk & 31) * 64;
  const int b = bh >> 4, h = bh & 15;
  const short* Qp = QKV + (size_t)b*SEQ*3072 + h*64;
  const short* Kp = Qp + DM;
  const short* Vp = Qp + 2*DM;
  float* attn_bh = attn_out + (size_t)bh * SEQ * SEQ;
  const int qw = q0 + w*16;

  // Q fragment for q = qw + row_l (reused as MFMA B operand)
  bf16x8 aq0 = *(const bf16x8*)(Qp + (size_t)(qw + row_l)*3072 + kg*8);
  bf16x8 aq1 = *(const bf16x8*)(Qp + (size_t)(qw + row_l)*3072 + 32 + kg*8);

  // ---- pass 1: row sums of exp(s). Lane accumulates its own 4-key strip. ----
  float rsum = 0.f;
  for (int kt = 0; kt < 32; ++kt) {
#pragma unroll
    for (int i = 0; i < 2; ++i) {
      int idx = i*256 + t;
      int kr = idx >> 3, cb = (idx & 7) * 8;
      *(bf16x8*)&Ks[kr*72 + cb] = *(const bf16x8*)(Kp + (size_t)(kt*64 + kr)*3072 + cb);
    }
    __syncthreads();
#pragma unroll
    for (int nt = 0; nt < 4; ++nt) {
      bf16x8 bk0 = *(const bf16x8*)&Ks[(nt*16 + row_l)*72 + kg*8];
      bf16x8 bk1 = *(const bf16x8*)&Ks[(nt*16 + row_l)*72 + 32 + kg*8];
      f32x4 s = {0.f, 0.f, 0.f, 0.f};
      s = __builtin_amdgcn_mfma_f32_16x16x32_bf16(bk0, aq0, s, 0, 0, 0);
      s = __builtin_amdgcn_mfma_f32_16x16x32_bf16(bk1, aq1, s, 0, 0, 0);
#pragma unroll
      for (int r = 0; r < 4; ++r) rsum += __expf(s[r] * 0.125f);
    }
    __syncthreads();
  }
  rsum += __shfl_xor(rsum, 16);
  rsum += __shfl_xor(rsum, 32);
  const float inv = 1.f / rsum;

  f32x4 actx[4];
  {
    f32x4 z = {0.f, 0.f, 0.f, 0.f};
#pragma unroll
    for (int e = 0; e < 4; ++e) actx[e] = z;
  }
  // ---- pass 2: recompute S^T, write normalized attn (float4), P->Ps (in-wave),
  //      PV: ctx^T = V^T * P^T ----
  for (int kt = 0; kt < 32; ++kt) {
#pragma unroll
    for (int i = 0; i < 2; ++i) {
      int idx = i*256 + t;
      int kr = idx >> 3, cb = (idx & 7) * 8;
      *(bf16x8*)&Ks[kr*72 + cb] = *(const bf16x8*)(Kp + (size_t)(kt*64 + kr)*3072 + cb);
      bf16x8 vv = *(const bf16x8*)(Vp + (size_t)(kt*64 + kr)*3072 + cb);
#pragma unroll
      for (int j = 0; j < 8; ++j) Vt[(cb + j)*72 + kr] = vv[j];  // Vt[d][key]
    }
    __syncthreads();
#pragma unroll
    for (int nt = 0; nt < 4; ++nt) {
      bf16x8 bk0 = *(const bf16x8*)&Ks[(nt*16 + row_l)*72 + kg*8];
      bf16x8 bk1 = *(const bf16x8*)&Ks[(nt*16 + row_l)*72 + 32 + kg*8];
      f32x4 s = {0.f, 0.f, 0.f, 0.f};
      s = __builtin_amdgcn_mfma_f32_16x16x32_bf16(bk0, aq0, s, 0, 0, 0);
      s = __builtin_amdgcn_mfma_f32_16x16x32_bf16(bk1, aq1, s, 0, 0, 0);
      float4 p;
      p.x = __expf(s[0] * 0.125f) * inv;
      p.y = __expf(s[1] * 0.125f) * inv;
      p.z = __expf(s[2] * 0.125f) * inv;
      p.w = __expf(s[3] * 0.125f) * inv;
      // attn[q][key..key+3], q = qw+row_l, key = kt*64 + nt*16 + kg*4
      *(float4*)&attn_bh[(size_t)(qw + row_l)*SEQ + kt*64 + nt*16 + kg*4] = p;
      bf16x4 pb4;
      pb4[0] = f2b(p.x); pb4[1] = f2b(p.y); pb4[2] = f2b(p.z); pb4[3] = f2b(p.w);
      *(bf16x4*)&Ps[w][row_l*72 + nt*16 + kg*4] = pb4;
    }
    // in-wave relay: Ps writes by other lanes of THIS wave must land before reads
    asm volatile("s_waitcnt lgkmcnt(0)" ::: "memory");
    __builtin_amdgcn_sched_barrier(0);
#pragma unroll
    for (int half = 0; half < 2; ++half) {
      bf16x8 pb = *(const bf16x8*)&Ps[w][row_l*72 + half*32 + kg*8];   // P^T frag
#pragma unroll
      for (int e = 0; e < 4; ++e) {
        bf16x8 va = *(const bf16x8*)&Vt[(e*16 + row_l)*72 + half*32 + kg*8];  // V^T frag
        actx[e] = __builtin_amdgcn_mfma_f32_16x16x32_bf16(va, pb, actx[e], 0, 0, 0);
      }
    }
    __syncthreads();
  }
  // ctx epilogue: actx[e] holds ctx^T: row d = e*16+kg*4+r, col q = row_l.
  // Lane writes 4 consecutive bf16 (one short4) per e.
#pragma unroll
  for (int e = 0; e < 4; ++e) {
    bf16x4 o;
    o[0] = f2b(actx[e][0]); o[1] = f2b(actx[e][1]);
    o[2] = f2b(actx[e][2]); o[3] = f2b(actx[e][3]);
    *(bf16x4*)&ctx[(size_t)(b*SEQ + qw + row_l)*DM + h*64 + e*16 + kg*4] = o;
  }
}

// ---------------- launch ----------------

extern "C" void kernel_launch(void* const* d_in, const int* in_sizes, int n_in,
                              void* d_out, int out_size, void* d_ws, size_t ws_size,
                              hipStream_t stream) {
  const float* x    = (const float*)d_in[0];
  const float* Wq   = (const float*)d_in[1];
  const float* bq   = (const float*)d_in[2];
  const float* Wk   = (const float*)d_in[3];
  const float* bk   = (const float*)d_in[4];
  const float* Wv   = (const float*)d_in[5];
  const float* bv   = (const float*)d_in[6];
  const float* Wo   = (const float*)d_in[7];
  const float* bo   = (const float*)d_in[8];
  const float* gate = (const float*)d_in[9];
  const float* ent  = (const float*)d_in[10];

  char* ws = (char*)d_ws;
  short* xb   = (short*)(ws);                          // 4096x1024 bf16 (8 MB)
  short* Wcat = (short*)(ws + ((size_t)8  << 20));     // 3072x1024 bf16 (6 MB)
  short* Wob  = (short*)(ws + ((size_t)14 << 20));     // 1024x1024 bf16 (2 MB)
  float* bcat = (float*)(ws + ((size_t)16 << 20));     // 3072 f32
  short* QKV  = (short*)(ws + ((size_t)17 << 20));     // 4096x3072 bf16 (24 MB)
  short* ctxb = (short*)(ws + ((size_t)41 << 20));     // 4096x1024 bf16 (8 MB)

  float* outp  = (float*)d_out;
  float* attnp = outp + (size_t)MROWS * DM;

  k_conv<<<2048, 256, 0, stream>>>(x, xb, MROWS*DM);
  k_conv_gate<<<512, 256, 0, stream>>>(Wq, gate, Wcat);
  k_went<<<dim3(1024, 4), 256, 0, stream>>>(Wk, ent, Wcat + (size_t)1024*DM);
  k_conv<<<512, 256, 0, stream>>>(Wv, Wcat + (size_t)2048*DM, 1024*1024);
  k_conv<<<512, 256, 0, stream>>>(Wo, Wob, 1024*1024);
  k_bias<<<12, 256, 0, stream>>>(bq, bk, bv, gate, ent, bcat);

  gemm_bt<1><<<dim3(32, 24), 256, 0, stream>>>(xb, Wcat, bcat, QKV, MROWS, 3072, DM);
  attn_fused<<<1024, 256, 0, stream>>>(QKV, attnp, ctxb);
  gemm_bt<0><<<dim3(32, 8), 256, 0, stream>>>(ctxb, Wob, bo, outp, MROWS, DM, DM);
}